// Round 17
// baseline (316.174 us; speedup 1.0000x reference)
//
#include <hip/hip_runtime.h>
#include <math.h>

#define DIM 768
#define HEADS 12
#define DHEAD 64
#define NTOK 31
#define BATCH 512
#define MTOK (BATCH * NTOK)   /* 15872 */
#define HIDDEN 3072
#define QKVN 2304
#define MASK_VAL -987654321.0f

typedef short s16x8 __attribute__((ext_vector_type(8)));
typedef float f32x4 __attribute__((ext_vector_type(4)));
typedef float f32x16 __attribute__((ext_vector_type(16)));

static __device__ __forceinline__ float bs2f(unsigned short u) {
  unsigned int x = ((unsigned int)u) << 16;
  return __builtin_bit_cast(float, x);
}
static __device__ __forceinline__ unsigned short f2bs(float f) {
  unsigned int x = __builtin_bit_cast(unsigned int, f);
  x += 0x7fffu + ((x >> 16) & 1u);
  return (unsigned short)(x >> 16);
}

// async global->LDS, 16B per lane, wave-uniform LDS base + lane*16
static __device__ __forceinline__ void gload16(const unsigned short* g, unsigned short* l) {
  __builtin_amdgcn_global_load_lds(
      (const __attribute__((address_space(1))) unsigned int*)g,
      (__attribute__((address_space(3))) unsigned int*)l, 16, 0, 0);
}

static __device__ __forceinline__ float epi_apply(int EPI, float v, int col, size_t idx,
                                                  const float* bias, const void* resid) {
  if (EPI == 0) return v;
  if (EPI == 2) {
    float t = v + bias[col];
    float arg = 1.5957691216f * t * (1.f + 0.044715f * t * t);
    return t * __builtin_amdgcn_rcpf(1.f + __expf(-arg));
  }
  if (EPI == 3) return v + bias[col] + ((const float*)resid)[idx];
  return v + bias[col] + bs2f(((const unsigned short*)resid)[idx]);  // EPI==4
}

static __device__ __forceinline__ void epi_store(int EPI, void* outp, size_t idx, float t) {
  if (EPI == 4) ((float*)outp)[idx] = t;
  else ((unsigned short*)outp)[idx] = f2bs(t);
}

// ---------------- batched weight transposes: all flat [N][K] bf16 ----------------
__global__ __launch_bounds__(256) void transpose_all_kernel(
    const float* __restrict__ w_qkv, const float* __restrict__ w_o,
    const float* __restrict__ w1, const float* __restrict__ w2,
    unsigned short* __restrict__ wqkvT, unsigned short* __restrict__ woT,
    unsigned short* __restrict__ w1T, unsigned short* __restrict__ w2T) {
  int t = blockIdx.x;
  const float* w;
  unsigned short* wt;
  int K, N, tx;
  if (t < 432) { w = w_qkv; wt = wqkvT; K = DIM; N = QKVN; tx = QKVN / 64; }
  else if (t < 576) { t -= 432; w = w_o; wt = woT; K = DIM; N = DIM; tx = DIM / 64; }
  else if (t < 1152) { t -= 576; w = w1; wt = w1T; K = DIM; N = HIDDEN; tx = HIDDEN / 64; }
  else { t -= 1152; w = w2; wt = w2T; K = HIDDEN; N = DIM; tx = DIM / 64; }
  int n0 = (t % tx) * 64, k0 = (t / tx) * 64;

  __shared__ float tl[64][65];
  int tid = threadIdx.x;
  int r = tid >> 4, c4 = (tid & 15) * 4;
#pragma unroll
  for (int i = 0; i < 4; ++i) {
    float4 v = *(const float4*)(w + (size_t)(k0 + r + i * 16) * N + n0 + c4);
    tl[r + i * 16][c4] = v.x;
    tl[r + i * 16][c4 + 1] = v.y;
    tl[r + i * 16][c4 + 2] = v.z;
    tl[r + i * 16][c4 + 3] = v.w;
  }
  __syncthreads();
#pragma unroll
  for (int i = 0; i < 4; ++i) {
    int n = r + i * 16;
    ushort4 o;
    o.x = f2bs(tl[c4 + 0][n]);
    o.y = f2bs(tl[c4 + 1][n]);
    o.z = f2bs(tl[c4 + 2][n]);
    o.w = f2bs(tl[c4 + 3][n]);
    *(ushort4*)(wt + (size_t)(n0 + n) * K + k0 + c4) = o;
  }
}

// ---------------- LayerNorm (f32 in) ----------------
__global__ __launch_bounds__(256) void ln_kernel(const float* __restrict__ x,
                                                 const float* __restrict__ g,
                                                 const float* __restrict__ bta,
                                                 unsigned short* __restrict__ out) {
  int wid = threadIdx.x >> 6, lane = threadIdx.x & 63;
  size_t row = (size_t)blockIdx.x * 4 + wid;
  const float4* xr = (const float4*)(x + row * DIM);
  float4 v[3];
  v[0] = xr[lane];
  v[1] = xr[lane + 64];
  v[2] = xr[lane + 128];
  float s = 0.f, sq = 0.f;
#pragma unroll
  for (int i = 0; i < 3; ++i) {
    s += v[i].x + v[i].y + v[i].z + v[i].w;
    sq += v[i].x * v[i].x + v[i].y * v[i].y + v[i].z * v[i].z + v[i].w * v[i].w;
  }
#pragma unroll
  for (int off = 32; off; off >>= 1) {
    s += __shfl_xor(s, off);
    sq += __shfl_xor(sq, off);
  }
  float mu = s * (1.f / DIM);
  float var = sq * (1.f / DIM) - mu * mu;
  float rs = rsqrtf(var + 1e-5f);
#pragma unroll
  for (int i = 0; i < 3; ++i) {
    int col = i * 256 + lane * 4;
    float4 gg = *(const float4*)(g + col);
    float4 bb = *(const float4*)(bta + col);
    ushort4 o;
    o.x = f2bs((v[i].x - mu) * rs * gg.x + bb.x);
    o.y = f2bs((v[i].y - mu) * rs * gg.y + bb.y);
    o.z = f2bs((v[i].z - mu) * rs * gg.z + bb.z);
    o.w = f2bs((v[i].w - mu) * rs * gg.w + bb.w);
    *(ushort4*)(out + row * DIM + col) = o;
  }
}

// ---------------- LayerNorm (bf16 in) ----------------
__global__ __launch_bounds__(256) void ln_bf16_kernel(const unsigned short* __restrict__ x,
                                                      const float* __restrict__ g,
                                                      const float* __restrict__ bta,
                                                      unsigned short* __restrict__ out) {
  int wid = threadIdx.x >> 6, lane = threadIdx.x & 63;
  size_t row = (size_t)blockIdx.x * 4 + wid;
  const unsigned short* xr = x + row * DIM;
  float v[12];
#pragma unroll
  for (int i = 0; i < 3; ++i) {
    ushort4 u = *(const ushort4*)(xr + i * 256 + lane * 4);
    v[i * 4 + 0] = bs2f(u.x);
    v[i * 4 + 1] = bs2f(u.y);
    v[i * 4 + 2] = bs2f(u.z);
    v[i * 4 + 3] = bs2f(u.w);
  }
  float s = 0.f, sq = 0.f;
#pragma unroll
  for (int i = 0; i < 12; ++i) {
    s += v[i];
    sq += v[i] * v[i];
  }
#pragma unroll
  for (int off = 32; off; off >>= 1) {
    s += __shfl_xor(s, off);
    sq += __shfl_xor(sq, off);
  }
  float mu = s * (1.f / DIM);
  float var = sq * (1.f / DIM) - mu * mu;
  float rs = rsqrtf(var + 1e-5f);
#pragma unroll
  for (int i = 0; i < 3; ++i) {
    int col = i * 256 + lane * 4;
    float4 gg = *(const float4*)(g + col);
    float4 bb = *(const float4*)(bta + col);
    ushort4 o;
    o.x = f2bs((v[i * 4 + 0] - mu) * rs * gg.x + bb.x);
    o.y = f2bs((v[i * 4 + 1] - mu) * rs * gg.y + bb.y);
    o.z = f2bs((v[i * 4 + 2] - mu) * rs * gg.z + bb.z);
    o.w = f2bs((v[i * 4 + 3] - mu) * rs * gg.w + bb.w);
    *(ushort4*)(out + row * DIM + col) = o;
  }
}

// ============ pipelined persistent 8-phase 256x192 GEMM (qkv, proj, mlp2) ============
template <int CMH, int CS, int CB, int RBUF, int RMH, int RKH, int RB, int VM, int NORD,
          typename STF>
__device__ __forceinline__ void gphP(const char* aB0, const char* bKH0, const char* bKH1,
                                     s16x8 (&af2)[2][4], s16x8 (&bk2)[2][3],
                                     f32x4 (&acc)[8][3], STF&& stage) {
  stage();
  if (VM == 2) asm volatile("s_waitcnt vmcnt(2)");
  if (VM == 0) asm volatile("s_waitcnt vmcnt(0)");
  __builtin_amdgcn_s_barrier();
  if (!NORD) {
    const char* aP = aB0 + RBUF * 32768 + RKH * 16384 + RMH * 4096;
#pragma unroll
    for (int mi = 0; mi < 4; ++mi) af2[CS ^ 1][mi] = *(const s16x8*)(aP + mi * 1024);
    if (RMH == 0) {
      const char* bp = (RKH ? bKH1 : bKH0) + RBUF * 24576;
#pragma unroll
      for (int ni = 0; ni < 3; ++ni) bk2[RB][ni] = *(const s16x8*)(bp + ni * 2048);
    }
  }
  __builtin_amdgcn_s_setprio(1);
#pragma unroll
  for (int mi = 0; mi < 4; ++mi)
#pragma unroll
    for (int ni = 0; ni < 3; ++ni)
      acc[CMH * 4 + mi][ni] = __builtin_amdgcn_mfma_f32_16x16x32_bf16(
          af2[CS][mi], bk2[CB][ni], acc[CMH * 4 + mi][ni], 0, 0, 0);
  __builtin_amdgcn_s_setprio(0);
  __builtin_amdgcn_s_barrier();
}

template <int EPI, int TPB>
__device__ __forceinline__ void gemm192_body(
    const unsigned short* __restrict__ A, const unsigned short* __restrict__ Bt,
    void* __restrict__ outp, const float* __restrict__ bias,
    const void* __restrict__ resid, int M, int N, int K, int ntn) {
  __shared__ char ldsc[114688];  // 112 KiB
  int tid = threadIdx.x;
  int lane = tid & 63, w = tid >> 6;
  int wm = w >> 2, wn = w & 3;
  int fr = lane & 15, q = lane >> 4;

  int nwg = gridDim.x, orig = blockIdx.x;
  int qd = nwg >> 3, r8 = nwg & 7, xcd = orig & 7, loc = orig >> 3;
  int bid = (xcd < r8 ? xcd * (qd + 1) : r8 * (qd + 1) + (xcd - r8) * qd) + loc;

  int rdoffA = (q * 16) ^ (((fr >> 1) & 3) << 4);
  const char* aB0 = ldsc + (wm * 128 + fr) * 64 + rdoffA;
  int brow0 = wn * 48 + fr;
  int bsw = brow0 & 7;
  const char* bBase = ldsc + 65536 + brow0 * 128 + (q ^ (bsw & 3)) * 16;
  const char* bKH0 = bBase + ((0 ^ (bsw >> 2)) * 64);
  const char* bKH1 = bBase + ((1 ^ (bsw >> 2)) * 64);

  int srow = tid >> 2;
  int seoffA = (((tid & 3) ^ ((srow >> 1) & 3))) << 3;
  size_t rstep = (size_t)K * 256;
  int NT = K / 64;

#pragma unroll 1
  for (int tl = 0; tl < TPB; ++tl) {
    int tile = bid * TPB + tl;
    int m0 = (tile / ntn) * 256, n0 = (tile % ntn) * 192;

    const char* Ab = (const char*)A + ((size_t)(m0 + srow) * K + seoffA) * 2;
    const char* Bb2 = (const char*)Bt +
        ((size_t)(n0 + (tid >> 3)) * K + (((tid & 7) ^ ((tid >> 3) & 7)) * 8)) * 2;

    auto stgA = [&](int kh, int buf, int t) {
      const char* gp = Ab + t * 128 + kh * 64;
      unsigned short* lp = (unsigned short*)(ldsc + buf * 32768 + kh * 16384 + w * 1024);
      gload16((const unsigned short*)gp, lp);
      gload16((const unsigned short*)(gp + rstep), (unsigned short*)((char*)lp + 8192));
    };
    auto stgB = [&](int j, int buf, int t) {
      gload16((const unsigned short*)(Bb2 + (size_t)j * 128 * K + t * 128),
              (unsigned short*)(ldsc + 65536 + buf * 24576 + j * 8192 + w * 1024));
    };
    auto nop = [&] {};

    f32x4 acc[8][3] = {};
    s16x8 af2[2][4], bk2[2][3];

    stgA(0, 0, 0);
    stgA(1, 0, 0);
    stgB(0, 0, 0);
    stgB(1, 0, 0);
    stgB(2, 0, 0);
    stgA(0, 1, 1);
    asm volatile("s_waitcnt vmcnt(2)");
    __builtin_amdgcn_s_barrier();
    {
#pragma unroll
      for (int mi = 0; mi < 4; ++mi) af2[0][mi] = *(const s16x8*)(aB0 + mi * 1024);
#pragma unroll
      for (int ni = 0; ni < 3; ++ni) bk2[0][ni] = *(const s16x8*)(bKH0 + ni * 2048);
    }

    for (int t = 0; t + 3 < NT; t += 2) {
      gphP<0, 0, 0, 0, 1, 0, 0, -1, 0>(aB0, bKH0, bKH1, af2, bk2, acc,
          [&] { stgA(1, 1, t + 1); stgB(0, 1, t + 1); stgB(1, 1, t + 1); });
      gphP<1, 1, 0, 0, 0, 1, 1, -1, 0>(aB0, bKH0, bKH1, af2, bk2, acc,
          [&] { stgB(2, 1, t + 1); });
      gphP<0, 0, 1, 0, 1, 1, 0, -1, 0>(aB0, bKH0, bKH1, af2, bk2, acc,
          [&] { stgA(0, 0, t + 2); });
      gphP<1, 1, 1, 1, 0, 0, 0, 2, 0>(aB0, bKH0, bKH1, af2, bk2, acc, nop);
      gphP<0, 0, 0, 1, 1, 0, 0, -1, 0>(aB0, bKH0, bKH1, af2, bk2, acc,
          [&] { stgA(1, 0, t + 2); stgB(0, 0, t + 2); stgB(1, 0, t + 2); });
      gphP<1, 1, 0, 1, 0, 1, 1, -1, 0>(aB0, bKH0, bKH1, af2, bk2, acc,
          [&] { stgB(2, 0, t + 2); });
      gphP<0, 0, 1, 1, 1, 1, 0, -1, 0>(aB0, bKH0, bKH1, af2, bk2, acc,
          [&] { stgA(0, 1, t + 3); });
      gphP<1, 1, 1, 0, 0, 0, 0, 2, 0>(aB0, bKH0, bKH1, af2, bk2, acc, nop);
    }
    gphP<0, 0, 0, 0, 1, 0, 0, -1, 0>(aB0, bKH0, bKH1, af2, bk2, acc,
        [&] { stgA(1, 1, NT - 1); stgB(0, 1, NT - 1); stgB(1, 1, NT - 1); });
    gphP<1, 1, 0, 0, 0, 1, 1, -1, 0>(aB0, bKH0, bKH1, af2, bk2, acc,
        [&] { stgB(2, 1, NT - 1); });
    gphP<0, 0, 1, 0, 1, 1, 0, -1, 0>(aB0, bKH0, bKH1, af2, bk2, acc, nop);
    gphP<1, 1, 1, 1, 0, 0, 0, 0, 0>(aB0, bKH0, bKH1, af2, bk2, acc, nop);
    gphP<0, 0, 0, 1, 1, 0, 0, -1, 0>(aB0, bKH0, bKH1, af2, bk2, acc, nop);
    gphP<1, 1, 0, 1, 0, 1, 1, -1, 0>(aB0, bKH0, bKH1, af2, bk2, acc, nop);
    gphP<0, 0, 1, 1, 1, 1, 0, -1, 0>(aB0, bKH0, bKH1, af2, bk2, acc, nop);
    gphP<1, 1, 1, 0, 0, 0, 0, -1, 1>(aB0, bKH0, bKH1, af2, bk2, acc, nop);

#pragma unroll
    for (int am = 0; am < 8; ++am)
#pragma unroll
      for (int ni = 0; ni < 3; ++ni)
#pragma unroll
        for (int rr = 0; rr < 4; ++rr) {
          int row = m0 + wm * 128 + am * 16 + q * 4 + rr;
          int col = n0 + wn * 48 + ni * 16 + fr;
          size_t idx = (size_t)row * N + col;
          epi_store(EPI, outp, idx, epi_apply(EPI, acc[am][ni][rr], col, idx, bias, resid));
        }
  }
}

// ============ 32x32x16 merged-phase persistent 256x256 GEMM (mlp1) ============
// Phase = full K=32 (one kh): 16x mfma_32x32x16 (2x FLOP of old phase), 12 frag
// reads, 2 stages, 2 barriers. 4 phases per 2 K-tiles.
// Frag maps: A/B row=lane&31, k-octet=(lane>>5)*8 (extension of verified 16x16
// map); C/D col=lane&31, row=(reg&3)+8*(reg>>2)+4*(lane>>5) (HW-verified m74/m101).
// Swizzle: 16B slot ^= ((r>>1)&3)^((r>>3)&3), both-sides (stage source + read).
// Ledger (4 loads/phase; queue per iter: P0{A1b1,B1b1} P1{B0b0',A0b0'}
// P2{B1b0',A1b0'} P3{B0b1',A0b1'}): every phase-q top-read confirmed by vmcnt(8)
// at q-1 (uniform); WAR all 1-full-phase gaps. Final iter: P0 stages t+1 only,
// waits 8/4/0/none.
template <int BUF, int KH, int VM, typename STF>
__device__ __forceinline__ void gph32(const char* aB, const char* bB, int o0, int o1,
                                      f32x16 (&acc)[4][2], STF&& stage) {
  const char* aP = aB + BUF * 32768 + KH * 16384;
  const char* bP = bB + BUF * 32768 + KH * 16384;
  s16x8 af[4][2], bk[2][2];
#pragma unroll
  for (int mt = 0; mt < 4; ++mt) {
    af[mt][0] = *(const s16x8*)(aP + mt * 2048 + o0);
    af[mt][1] = *(const s16x8*)(aP + mt * 2048 + o1);
  }
#pragma unroll
  for (int nt = 0; nt < 2; ++nt) {
    bk[nt][0] = *(const s16x8*)(bP + nt * 2048 + o0);
    bk[nt][1] = *(const s16x8*)(bP + nt * 2048 + o1);
  }
  stage();
  if (VM == 8) asm volatile("s_waitcnt vmcnt(8)");
  if (VM == 4) asm volatile("s_waitcnt vmcnt(4)");
  if (VM == 0) asm volatile("s_waitcnt vmcnt(0)");
  __builtin_amdgcn_s_barrier();
  asm volatile("s_waitcnt lgkmcnt(0)");
  __builtin_amdgcn_s_setprio(1);
#pragma unroll
  for (int mt = 0; mt < 4; ++mt)
#pragma unroll
    for (int nt = 0; nt < 2; ++nt) {
      acc[mt][nt] =
          __builtin_amdgcn_mfma_f32_32x32x16_bf16(af[mt][0], bk[nt][0], acc[mt][nt], 0, 0, 0);
      acc[mt][nt] =
          __builtin_amdgcn_mfma_f32_32x32x16_bf16(af[mt][1], bk[nt][1], acc[mt][nt], 0, 0, 0);
    }
  __builtin_amdgcn_s_setprio(0);
  __builtin_amdgcn_s_barrier();
}

template <int EPI, int TPB>
__device__ __forceinline__ void gemm256x_body(
    const unsigned short* __restrict__ A, const unsigned short* __restrict__ Bt,
    void* __restrict__ outp, const float* __restrict__ bias,
    const void* __restrict__ resid, int M, int N, int K, int ntn) {
  __shared__ char ldsc[131072];  // [mat A@0|B@65536][buf(2)][kh(2)][256][32]
  int tid = threadIdx.x;
  int lane = tid & 63, w = tid >> 6;
  int wm = w >> 2, wn = w & 3;
  int l31 = lane & 31, lh = lane >> 5;

  int nwg = gridDim.x, orig = blockIdx.x;
  int qd = nwg >> 3, r8 = nwg & 7, xcd = orig & 7, loc = orig >> 3;
  int bid = (xcd < r8 ? xcd * (qd + 1) : r8 * (qd + 1) + (xcd - r8) * qd) + loc;

  int swz = ((l31 >> 1) & 3) ^ ((l31 >> 3) & 3);
  int o0 = ((0 + lh) ^ swz) * 16;  // ksub 0
  int o1 = ((2 + lh) ^ swz) * 16;  // ksub 1
  const char* aB = ldsc + (wm * 128 + l31) * 64;
  const char* bB = ldsc + 65536 + (wn * 64 + l31) * 64;

  int srow = tid >> 2;
  int seoff = (((tid & 3) ^ ((srow >> 1) & 3) ^ ((srow >> 3) & 3))) << 3;
  size_t rstep = (size_t)K * 256;
  int NT = K / 64;

#pragma unroll 1
  for (int tl = 0; tl < TPB; ++tl) {
    int tile = bid * TPB + tl;
    int m0 = (tile / ntn) * 256, n0 = (tile % ntn) * 256;

    const char* Ab = (const char*)A + ((size_t)(m0 + srow) * K + seoff) * 2;
    const char* Bb = (const char*)Bt + ((size_t)(n0 + srow) * K + seoff) * 2;

    auto stg = [&](int mat, int kh, int buf, int t) {
      const char* gp = (mat ? Bb : Ab) + t * 128 + kh * 64;
      unsigned short* lp =
          (unsigned short*)(ldsc + mat * 65536 + buf * 32768 + kh * 16384 + w * 1024);
      gload16((const unsigned short*)gp, lp);
      gload16((const unsigned short*)(gp + rstep), (unsigned short*)((char*)lp + 8192));
    };
    auto nop = [&] {};

    f32x16 acc[4][2] = {};

    // prologue: b0kh0{B,A}, b0kh1{B,A}, b1kh0{B,A}; confirm b0kh0 (first 4 loads)
    stg(1, 0, 0, 0);
    stg(0, 0, 0, 0);
    stg(1, 1, 0, 0);
    stg(0, 1, 0, 0);
    stg(1, 0, 1, 1);
    stg(0, 0, 1, 1);
    asm volatile("s_waitcnt vmcnt(8)");
    __builtin_amdgcn_s_barrier();

    for (int t = 0; t + 3 < NT; t += 2) {
      gph32<0, 0, 8>(aB, bB, o0, o1, acc,
                     [&] { stg(0, 1, 1, t + 1); stg(1, 1, 1, t + 1); });
      gph32<0, 1, 8>(aB, bB, o0, o1, acc,
                     [&] { stg(1, 0, 0, t + 2); stg(0, 0, 0, t + 2); });
      gph32<1, 0, 8>(aB, bB, o0, o1, acc,
                     [&] { stg(1, 1, 0, t + 2); stg(0, 1, 0, t + 2); });
      gph32<1, 1, 8>(aB, bB, o0, o1, acc,
                     [&] { stg(1, 0, 1, t + 3); stg(0, 0, 1, t + 3); });
    }
    // final iteration: tiles NT-2 (buf0), NT-1 (buf1)
    gph32<0, 0, 8>(aB, bB, o0, o1, acc,
                   [&] { stg(0, 1, 1, NT - 1); stg(1, 1, 1, NT - 1); });
    gph32<0, 1, 4>(aB, bB, o0, o1, acc, nop);
    gph32<1, 0, 0>(aB, bB, o0, o1, acc, nop);
    gph32<1, 1, -1>(aB, bB, o0, o1, acc, nop);

    // C-write: row = m0+wm*128+mt*32+(reg&3)+8*(reg>>2)+4*lh, col = n0+wn*64+nt*32+l31
#pragma unroll
    for (int mt = 0; mt < 4; ++mt)
#pragma unroll
      for (int nt = 0; nt < 2; ++nt)
#pragma unroll
        for (int reg = 0; reg < 16; ++reg) {
          int row = m0 + wm * 128 + mt * 32 + (reg & 3) + 8 * (reg >> 2) + 4 * lh;
          int col = n0 + wn * 64 + nt * 32 + l31;
          size_t idx = (size_t)row * N + col;
          epi_store(EPI, outp, idx, epi_apply(EPI, acc[mt][nt][reg], col, idx, bias, resid));
        }
  }
}

// named wrappers for rocprof attribution
__global__ __launch_bounds__(512, 2) void gemm_qkv(const unsigned short* A,
                                                   const unsigned short* Bt, void* o,
                                                   const float* b, const void* r, int M,
                                                   int N, int K, int ntn) {
  gemm192_body<0, 3>(A, Bt, o, b, r, M, N, K, ntn);
}
__global__ __launch_bounds__(512, 2) void gemm_mlp1(const unsigned short* A,
                                                    const unsigned short* Bt, void* o,
                                                    const float* b, const void* r, int M,
                                                    int N, int K, int ntn) {
  gemm256x_body<2, 3>(A, Bt, o, b, r, M, N, K, ntn);
}
__global__ __launch_bounds__(512, 2) void gemm_proj(const unsigned short* A,
                                                    const unsigned short* Bt, void* o,
                                                    const float* b, const void* r, int M,
                                                    int N, int K, int ntn) {
  gemm192_body<3, 1>(A, Bt, o, b, r, M, N, K, ntn);
}
__global__ __launch_bounds__(512, 2) void gemm_mlp2(const unsigned short* A,
                                                    const unsigned short* Bt, void* o,
                                                    const float* b, const void* r, int M,
                                                    int N, int K, int ntn) {
  gemm192_body<4, 1>(A, Bt, o, b, r, M, N, K, ntn);
}

// ---------------- MFMA attention: one wave per (batch, head) ----------------
__global__ __launch_bounds__(256) void attn_mfma_kernel(const unsigned short* __restrict__ qkv,
                                                        const float* __restrict__ scale,
                                                        unsigned short* __restrict__ ao) {
  __shared__ unsigned short Vt[4][64][40];
  __shared__ unsigned short Pl[4][32][32];
  int wid = threadIdx.x >> 6, lane = threadIdx.x & 63;
  int pair = blockIdx.x * 4 + wid;
  int b = pair / HEADS, h = pair % HEADS;
  const unsigned short* base = qkv + (size_t)b * NTOK * QKVN + h * DHEAD;
  const unsigned short* Qp = base;
  const unsigned short* Kp = base + 768;
  const unsigned short* Vp = base + 1536;

  int c = lane & 15, q = lane >> 4;
  int oct = q * 8;

  unsigned short vcol[NTOK];
#pragma unroll
  for (int j = 0; j < NTOK; ++j) vcol[j] = Vp[(size_t)j * QKVN + lane];
#pragma unroll
  for (int j = 0; j < NTOK; ++j) Vt[wid][lane][j] = vcol[j];
  Vt[wid][lane][31] = 0;

  s16x8 kf[2][2] = {{{0}}}, qf[2][2] = {{{0}}};
#pragma unroll
  for (int t = 0; t < 2; ++t) {
    int row = t * 16 + c;
    if (row < NTOK) {
#pragma unroll
      for (int s = 0; s < 2; ++s) {
        kf[t][s] = *(const s16x8*)(Kp + (size_t)row * QKVN + s * 32 + oct);
        qf[t][s] = *(const s16x8*)(Qp + (size_t)row * QKVN + s * 32 + oct);
      }
    }
  }

  f32x4 st[2][2] = {};
#pragma unroll
  for (int jt = 0; jt < 2; ++jt)
#pragma unroll
    for (int it = 0; it < 2; ++it)
#pragma unroll
      for (int s = 0; s < 2; ++s)
        st[jt][it] =
            __builtin_amdgcn_mfma_f32_16x16x32_bf16(kf[jt][s], qf[it][s], st[jt][it], 0, 0, 0);

  float scl = scale[h];
  float p[2][2][4];
#pragma unroll
  for (int it = 0; it < 2; ++it)
#pragma unroll
    for (int jt = 0; jt < 2; ++jt)
#pragma unroll
      for (int r = 0; r < 4; ++r) {
        int j = jt * 16 + 4 * q + r;
        int i = it * 16 + c;
        float v = st[jt][it][r] * scl;
        if (j == 31 || j == i) v = MASK_VAL;
        p[it][jt][r] = v;
      }
#pragma unroll
  for (int it = 0; it < 2; ++it) {
    float m = p[it][0][0];
#pragma unroll
    for (int jt = 0; jt < 2; ++jt)
#pragma unroll
      for (int r = 0; r < 4; ++r) m = fmaxf(m, p[it][jt][r]);
    m = fmaxf(m, __shfl_xor(m, 16));
    m = fmaxf(m, __shfl_xor(m, 32));
    float s = 0.f;
#pragma unroll
    for (int jt = 0; jt < 2; ++jt)
#pragma unroll
      for (int r = 0; r < 4; ++r) {
        float e = __expf(p[it][jt][r] - m);
        p[it][jt][r] = e;
        s += e;
      }
    s += __shfl_xor(s, 16);
    s += __shfl_xor(s, 32);
    float inv = __builtin_amdgcn_rcpf(s);
#pragma unroll
    for (int jt = 0; jt < 2; ++jt)
#pragma unroll
      for (int r = 0; r < 4; ++r) p[it][jt][r] *= inv;
  }
#pragma unroll
  for (int it = 0; it < 2; ++it)
#pragma unroll
    for (int jt = 0; jt < 2; ++jt) {
      unsigned int w0 =
          (unsigned int)f2bs(p[it][jt][0]) | ((unsigned int)f2bs(p[it][jt][1]) << 16);
      unsigned int w1 =
          (unsigned int)f2bs(p[it][jt][2]) | ((unsigned int)f2bs(p[it][jt][3]) << 16);
      uint2 pk = {w0, w1};
      *(uint2*)&Pl[wid][it * 16 + c][jt * 16 + 4 * q] = pk;
    }

  s16x8 pa[2];
#pragma unroll
  for (int it = 0; it < 2; ++it) pa[it] = *(const s16x8*)&Pl[wid][it * 16 + c][oct];
  f32x4 o[2][4];
#pragma unroll
  for (int it = 0; it < 2; ++it)
#pragma unroll
    for (int dt = 0; dt < 4; ++dt) {
      s16x8 vb = *(const s16x8*)&Vt[wid][dt * 16 + c][oct];
      f32x4 z = {0.f, 0.f, 0.f, 0.f};
      o[it][dt] = __builtin_amdgcn_mfma_f32_16x16x32_bf16(pa[it], vb, z, 0, 0, 0);
    }
#pragma unroll
  for (int it = 0; it < 2; ++it)
#pragma unroll
    for (int r = 0; r < 4; ++r) {
      int i = it * 16 + 4 * q + r;
      if (i < NTOK) {
        size_t rowoff = ((size_t)b * NTOK + i) * DIM + h * DHEAD;
#pragma unroll
        for (int dt = 0; dt < 4; ++dt) ao[rowoff + dt * 16 + c] = f2bs(o[it][dt][r]);
      }
    }
}

// ---------------- launcher ----------------
extern "C" void kernel_launch(void* const* d_in, const int* in_sizes, int n_in,
                              void* d_out, int out_size, void* d_ws, size_t ws_size,
                              hipStream_t stream) {
  (void)in_sizes; (void)n_in; (void)out_size; (void)ws_size;
  const float* x = (const float*)d_in[0];
  const float* ln1_g = (const float*)d_in[1];
  const float* ln1_b = (const float*)d_in[2];
  const float* w_qkv = (const float*)d_in[3];
  const float* scale = (const float*)d_in[4];
  const float* w_o = (const float*)d_in[5];
  const float* b_o = (const float*)d_in[6];
  const float* ln2_g = (const float*)d_in[7];
  const float* ln2_b = (const float*)d_in[8];
  const float* w1 = (const float*)d_in[9];
  const float* b1 = (const float*)d_in[10];
  const float* w2 = (const float*)d_in[11];
  const float* b2 = (const float*)d_in[12];

  char* ws = (char*)d_ws;
  unsigned short* buf1 = (unsigned short*)(ws + 0);
  unsigned short* qkv_bf = (unsigned short*)(ws + 24379392);
  unsigned short* x2 = (unsigned short*)(ws + 24379392);  // aliases qkv (qkv dead)
  unsigned short* g_bf = (unsigned short*)(ws + 97517568);
  unsigned short* wqkvT = (unsigned short*)(ws + 195035136);  // flat [2304][768]
  unsigned short* woT = (unsigned short*)(ws + 198574080);    // flat [768][768]
  unsigned short* w1T = (unsigned short*)(ws + 199753728);    // flat [3072][768]
  unsigned short* w2T = (unsigned short*)(ws + 204472320);    // flat [768][3072]

  transpose_all_kernel<<<1728, 256, 0, stream>>>(w_qkv, w_o, w1, w2, wqkvT, woT, w1T, w2T);

  ln_kernel<<<MTOK / 4, 256, 0, stream>>>(x, ln1_g, ln1_b, buf1);
  // qkv GEMM   [256x192, 744 tiles, TPB=3 -> grid 248]
  gemm_qkv<<<248, 512, 0, stream>>>(
      buf1, wqkvT, qkv_bf, nullptr, nullptr, MTOK, QKVN, DIM, QKVN / 192);
  attn_mfma_kernel<<<(BATCH * HEADS) / 4, 256, 0, stream>>>(qkv_bf, scale, buf1);
  // proj + residual(x, f32) -> x2 (bf16)   [248 tiles, TPB=1]
  gemm_proj<<<248, 512, 0, stream>>>(
      buf1, woT, x2, b_o, x, MTOK, DIM, DIM, DIM / 192);
  ln_bf16_kernel<<<MTOK / 4, 256, 0, stream>>>(x2, ln2_g, ln2_b, buf1);
  // mlp1 + tanh-GELU   [256x256 32x32-MFMA, 744 tiles, TPB=3 -> grid 248]
  gemm_mlp1<<<248, 512, 0, stream>>>(
      buf1, w1T, g_bf, b1, nullptr, MTOK, HIDDEN, DIM, HIDDEN / 256);
  // mlp2 + residual(x2, bf16) -> out (f32)   [248 tiles, TPB=1]
  gemm_mlp2<<<248, 512, 0, stream>>>(
      g_bf, w2T, (float*)d_out, b2, x2, MTOK, DIM, HIDDEN, DIM / 192);
}

// Round 18
// 310.723 us; speedup vs baseline: 1.0175x; 1.0175x over previous
//
#include <hip/hip_runtime.h>
#include <math.h>

#define DIM 768
#define HEADS 12
#define DHEAD 64
#define NTOK 31
#define BATCH 512
#define MTOK (BATCH * NTOK)   /* 15872 */
#define HIDDEN 3072
#define QKVN 2304
#define MASK_VAL -987654321.0f

typedef short s16x8 __attribute__((ext_vector_type(8)));
typedef float f32x4 __attribute__((ext_vector_type(4)));

static __device__ __forceinline__ float bs2f(unsigned short u) {
  unsigned int x = ((unsigned int)u) << 16;
  return __builtin_bit_cast(float, x);
}
static __device__ __forceinline__ unsigned short f2bs(float f) {
  unsigned int x = __builtin_bit_cast(unsigned int, f);
  x += 0x7fffu + ((x >> 16) & 1u);
  return (unsigned short)(x >> 16);
}

// async global->LDS, 16B per lane, wave-uniform LDS base + lane*16
static __device__ __forceinline__ void gload16(const unsigned short* g, unsigned short* l) {
  __builtin_amdgcn_global_load_lds(
      (const __attribute__((address_space(1))) unsigned int*)g,
      (__attribute__((address_space(3))) unsigned int*)l, 16, 0, 0);
}

static __device__ __forceinline__ float epi_apply(int EPI, float v, int col, size_t idx,
                                                  const float* bias, const void* resid) {
  if (EPI == 0) return v;
  if (EPI == 2) {
    float t = v + bias[col];
    float arg = 1.5957691216f * t * (1.f + 0.044715f * t * t);
    return t * __builtin_amdgcn_rcpf(1.f + __expf(-arg));
  }
  if (EPI == 3) return v + bias[col] + ((const float*)resid)[idx];
  return v + bias[col] + bs2f(((const unsigned short*)resid)[idx]);  // EPI==4
}

static __device__ __forceinline__ void epi_store(int EPI, void* outp, size_t idx, float t) {
  if (EPI == 4) ((float*)outp)[idx] = t;
  else ((unsigned short*)outp)[idx] = f2bs(t);
}

// ---------------- batched weight transposes: all flat [N][K] bf16 ----------------
__global__ __launch_bounds__(256) void transpose_all_kernel(
    const float* __restrict__ w_qkv, const float* __restrict__ w_o,
    const float* __restrict__ w1, const float* __restrict__ w2,
    unsigned short* __restrict__ wqkvT, unsigned short* __restrict__ woT,
    unsigned short* __restrict__ w1T, unsigned short* __restrict__ w2T) {
  int t = blockIdx.x;
  const float* w;
  unsigned short* wt;
  int K, N, tx;
  if (t < 432) { w = w_qkv; wt = wqkvT; K = DIM; N = QKVN; tx = QKVN / 64; }
  else if (t < 576) { t -= 432; w = w_o; wt = woT; K = DIM; N = DIM; tx = DIM / 64; }
  else if (t < 1152) { t -= 576; w = w1; wt = w1T; K = DIM; N = HIDDEN; tx = HIDDEN / 64; }
  else { t -= 1152; w = w2; wt = w2T; K = HIDDEN; N = DIM; tx = DIM / 64; }
  int n0 = (t % tx) * 64, k0 = (t / tx) * 64;

  __shared__ float tl[64][65];
  int tid = threadIdx.x;
  int r = tid >> 4, c4 = (tid & 15) * 4;
#pragma unroll
  for (int i = 0; i < 4; ++i) {
    float4 v = *(const float4*)(w + (size_t)(k0 + r + i * 16) * N + n0 + c4);
    tl[r + i * 16][c4] = v.x;
    tl[r + i * 16][c4 + 1] = v.y;
    tl[r + i * 16][c4 + 2] = v.z;
    tl[r + i * 16][c4 + 3] = v.w;
  }
  __syncthreads();
#pragma unroll
  for (int i = 0; i < 4; ++i) {
    int n = r + i * 16;
    ushort4 o;
    o.x = f2bs(tl[c4 + 0][n]);
    o.y = f2bs(tl[c4 + 1][n]);
    o.z = f2bs(tl[c4 + 2][n]);
    o.w = f2bs(tl[c4 + 3][n]);
    *(ushort4*)(wt + (size_t)(n0 + n) * K + k0 + c4) = o;
  }
}

// ---------------- LayerNorm (f32 in) ----------------
__global__ __launch_bounds__(256) void ln_kernel(const float* __restrict__ x,
                                                 const float* __restrict__ g,
                                                 const float* __restrict__ bta,
                                                 unsigned short* __restrict__ out) {
  int wid = threadIdx.x >> 6, lane = threadIdx.x & 63;
  size_t row = (size_t)blockIdx.x * 4 + wid;
  const float4* xr = (const float4*)(x + row * DIM);
  float4 v[3];
  v[0] = xr[lane];
  v[1] = xr[lane + 64];
  v[2] = xr[lane + 128];
  float s = 0.f, sq = 0.f;
#pragma unroll
  for (int i = 0; i < 3; ++i) {
    s += v[i].x + v[i].y + v[i].z + v[i].w;
    sq += v[i].x * v[i].x + v[i].y * v[i].y + v[i].z * v[i].z + v[i].w * v[i].w;
  }
#pragma unroll
  for (int off = 32; off; off >>= 1) {
    s += __shfl_xor(s, off);
    sq += __shfl_xor(sq, off);
  }
  float mu = s * (1.f / DIM);
  float var = sq * (1.f / DIM) - mu * mu;
  float rs = rsqrtf(var + 1e-5f);
#pragma unroll
  for (int i = 0; i < 3; ++i) {
    int col = i * 256 + lane * 4;
    float4 gg = *(const float4*)(g + col);
    float4 bb = *(const float4*)(bta + col);
    ushort4 o;
    o.x = f2bs((v[i].x - mu) * rs * gg.x + bb.x);
    o.y = f2bs((v[i].y - mu) * rs * gg.y + bb.y);
    o.z = f2bs((v[i].z - mu) * rs * gg.z + bb.z);
    o.w = f2bs((v[i].w - mu) * rs * gg.w + bb.w);
    *(ushort4*)(out + row * DIM + col) = o;
  }
}

// ---------------- LayerNorm (bf16 in) ----------------
__global__ __launch_bounds__(256) void ln_bf16_kernel(const unsigned short* __restrict__ x,
                                                      const float* __restrict__ g,
                                                      const float* __restrict__ bta,
                                                      unsigned short* __restrict__ out) {
  int wid = threadIdx.x >> 6, lane = threadIdx.x & 63;
  size_t row = (size_t)blockIdx.x * 4 + wid;
  const unsigned short* xr = x + row * DIM;
  float v[12];
#pragma unroll
  for (int i = 0; i < 3; ++i) {
    ushort4 u = *(const ushort4*)(xr + i * 256 + lane * 4);
    v[i * 4 + 0] = bs2f(u.x);
    v[i * 4 + 1] = bs2f(u.y);
    v[i * 4 + 2] = bs2f(u.z);
    v[i * 4 + 3] = bs2f(u.w);
  }
  float s = 0.f, sq = 0.f;
#pragma unroll
  for (int i = 0; i < 12; ++i) {
    s += v[i];
    sq += v[i] * v[i];
  }
#pragma unroll
  for (int off = 32; off; off >>= 1) {
    s += __shfl_xor(s, off);
    sq += __shfl_xor(sq, off);
  }
  float mu = s * (1.f / DIM);
  float var = sq * (1.f / DIM) - mu * mu;
  float rs = rsqrtf(var + 1e-5f);
#pragma unroll
  for (int i = 0; i < 3; ++i) {
    int col = i * 256 + lane * 4;
    float4 gg = *(const float4*)(g + col);
    float4 bb = *(const float4*)(bta + col);
    ushort4 o;
    o.x = f2bs((v[i * 4 + 0] - mu) * rs * gg.x + bb.x);
    o.y = f2bs((v[i * 4 + 1] - mu) * rs * gg.y + bb.y);
    o.z = f2bs((v[i * 4 + 2] - mu) * rs * gg.z + bb.z);
    o.w = f2bs((v[i * 4 + 3] - mu) * rs * gg.w + bb.w);
    *(ushort4*)(out + row * DIM + col) = o;
  }
}

// ============ pipelined persistent 8-phase 256x192 GEMM (qkv, proj, mlp2) ============
template <int CMH, int CS, int CB, int RBUF, int RMH, int RKH, int RB, int VM, int NORD,
          typename STF>
__device__ __forceinline__ void gphP(const char* aB0, const char* bKH0, const char* bKH1,
                                     s16x8 (&af2)[2][4], s16x8 (&bk2)[2][3],
                                     f32x4 (&acc)[8][3], STF&& stage) {
  stage();
  if (VM == 2) asm volatile("s_waitcnt vmcnt(2)");
  if (VM == 0) asm volatile("s_waitcnt vmcnt(0)");
  __builtin_amdgcn_s_barrier();
  if (!NORD) {
    const char* aP = aB0 + RBUF * 32768 + RKH * 16384 + RMH * 4096;
#pragma unroll
    for (int mi = 0; mi < 4; ++mi) af2[CS ^ 1][mi] = *(const s16x8*)(aP + mi * 1024);
    if (RMH == 0) {
      const char* bp = (RKH ? bKH1 : bKH0) + RBUF * 24576;
#pragma unroll
      for (int ni = 0; ni < 3; ++ni) bk2[RB][ni] = *(const s16x8*)(bp + ni * 2048);
    }
  }
  __builtin_amdgcn_s_setprio(1);
#pragma unroll
  for (int mi = 0; mi < 4; ++mi)
#pragma unroll
    for (int ni = 0; ni < 3; ++ni)
      acc[CMH * 4 + mi][ni] = __builtin_amdgcn_mfma_f32_16x16x32_bf16(
          af2[CS][mi], bk2[CB][ni], acc[CMH * 4 + mi][ni], 0, 0, 0);
  __builtin_amdgcn_s_setprio(0);
  __builtin_amdgcn_s_barrier();
}

template <int EPI, int TPB>
__device__ __forceinline__ void gemm192_body(
    const unsigned short* __restrict__ A, const unsigned short* __restrict__ Bt,
    void* __restrict__ outp, const float* __restrict__ bias,
    const void* __restrict__ resid, int M, int N, int K, int ntn) {
  __shared__ char ldsc[114688];  // 112 KiB
  int tid = threadIdx.x;
  int lane = tid & 63, w = tid >> 6;
  int wm = w >> 2, wn = w & 3;
  int fr = lane & 15, q = lane >> 4;

  int nwg = gridDim.x, orig = blockIdx.x;
  int qd = nwg >> 3, r8 = nwg & 7, xcd = orig & 7, loc = orig >> 3;
  int bid = (xcd < r8 ? xcd * (qd + 1) : r8 * (qd + 1) + (xcd - r8) * qd) + loc;

  int rdoffA = (q * 16) ^ (((fr >> 1) & 3) << 4);
  const char* aB0 = ldsc + (wm * 128 + fr) * 64 + rdoffA;
  int brow0 = wn * 48 + fr;
  int bsw = brow0 & 7;
  const char* bBase = ldsc + 65536 + brow0 * 128 + (q ^ (bsw & 3)) * 16;
  const char* bKH0 = bBase + ((0 ^ (bsw >> 2)) * 64);
  const char* bKH1 = bBase + ((1 ^ (bsw >> 2)) * 64);

  int srow = tid >> 2;
  int seoffA = (((tid & 3) ^ ((srow >> 1) & 3))) << 3;
  size_t rstep = (size_t)K * 256;
  int NT = K / 64;

#pragma unroll 1
  for (int tl = 0; tl < TPB; ++tl) {
    int tile = bid * TPB + tl;
    int m0 = (tile / ntn) * 256, n0 = (tile % ntn) * 192;

    const char* Ab = (const char*)A + ((size_t)(m0 + srow) * K + seoffA) * 2;
    const char* Bb2 = (const char*)Bt +
        ((size_t)(n0 + (tid >> 3)) * K + (((tid & 7) ^ ((tid >> 3) & 7)) * 8)) * 2;

    auto stgA = [&](int kh, int buf, int t) {
      const char* gp = Ab + t * 128 + kh * 64;
      unsigned short* lp = (unsigned short*)(ldsc + buf * 32768 + kh * 16384 + w * 1024);
      gload16((const unsigned short*)gp, lp);
      gload16((const unsigned short*)(gp + rstep), (unsigned short*)((char*)lp + 8192));
    };
    auto stgB = [&](int j, int buf, int t) {
      gload16((const unsigned short*)(Bb2 + (size_t)j * 128 * K + t * 128),
              (unsigned short*)(ldsc + 65536 + buf * 24576 + j * 8192 + w * 1024));
    };
    auto nop = [&] {};

    f32x4 acc[8][3] = {};
    s16x8 af2[2][4], bk2[2][3];

    stgA(0, 0, 0);
    stgA(1, 0, 0);
    stgB(0, 0, 0);
    stgB(1, 0, 0);
    stgB(2, 0, 0);
    stgA(0, 1, 1);
    asm volatile("s_waitcnt vmcnt(2)");
    __builtin_amdgcn_s_barrier();
    {
#pragma unroll
      for (int mi = 0; mi < 4; ++mi) af2[0][mi] = *(const s16x8*)(aB0 + mi * 1024);
#pragma unroll
      for (int ni = 0; ni < 3; ++ni) bk2[0][ni] = *(const s16x8*)(bKH0 + ni * 2048);
    }

    for (int t = 0; t + 3 < NT; t += 2) {
      gphP<0, 0, 0, 0, 1, 0, 0, -1, 0>(aB0, bKH0, bKH1, af2, bk2, acc,
          [&] { stgA(1, 1, t + 1); stgB(0, 1, t + 1); stgB(1, 1, t + 1); });
      gphP<1, 1, 0, 0, 0, 1, 1, -1, 0>(aB0, bKH0, bKH1, af2, bk2, acc,
          [&] { stgB(2, 1, t + 1); });
      gphP<0, 0, 1, 0, 1, 1, 0, -1, 0>(aB0, bKH0, bKH1, af2, bk2, acc,
          [&] { stgA(0, 0, t + 2); });
      gphP<1, 1, 1, 1, 0, 0, 0, 2, 0>(aB0, bKH0, bKH1, af2, bk2, acc, nop);
      gphP<0, 0, 0, 1, 1, 0, 0, -1, 0>(aB0, bKH0, bKH1, af2, bk2, acc,
          [&] { stgA(1, 0, t + 2); stgB(0, 0, t + 2); stgB(1, 0, t + 2); });
      gphP<1, 1, 0, 1, 0, 1, 1, -1, 0>(aB0, bKH0, bKH1, af2, bk2, acc,
          [&] { stgB(2, 0, t + 2); });
      gphP<0, 0, 1, 1, 1, 1, 0, -1, 0>(aB0, bKH0, bKH1, af2, bk2, acc,
          [&] { stgA(0, 1, t + 3); });
      gphP<1, 1, 1, 0, 0, 0, 0, 2, 0>(aB0, bKH0, bKH1, af2, bk2, acc, nop);
    }
    gphP<0, 0, 0, 0, 1, 0, 0, -1, 0>(aB0, bKH0, bKH1, af2, bk2, acc,
        [&] { stgA(1, 1, NT - 1); stgB(0, 1, NT - 1); stgB(1, 1, NT - 1); });
    gphP<1, 1, 0, 0, 0, 1, 1, -1, 0>(aB0, bKH0, bKH1, af2, bk2, acc,
        [&] { stgB(2, 1, NT - 1); });
    gphP<0, 0, 1, 0, 1, 1, 0, -1, 0>(aB0, bKH0, bKH1, af2, bk2, acc, nop);
    gphP<1, 1, 1, 1, 0, 0, 0, 0, 0>(aB0, bKH0, bKH1, af2, bk2, acc, nop);
    gphP<0, 0, 0, 1, 1, 0, 0, -1, 0>(aB0, bKH0, bKH1, af2, bk2, acc, nop);
    gphP<1, 1, 0, 1, 0, 1, 1, -1, 0>(aB0, bKH0, bKH1, af2, bk2, acc, nop);
    gphP<0, 0, 1, 1, 1, 1, 0, -1, 0>(aB0, bKH0, bKH1, af2, bk2, acc, nop);
    gphP<1, 1, 1, 0, 0, 0, 0, -1, 1>(aB0, bKH0, bKH1, af2, bk2, acc, nop);

#pragma unroll
    for (int am = 0; am < 8; ++am)
#pragma unroll
      for (int ni = 0; ni < 3; ++ni)
#pragma unroll
        for (int rr = 0; rr < 4; ++rr) {
          int row = m0 + wm * 128 + am * 16 + q * 4 + rr;
          int col = n0 + wn * 48 + ni * 16 + fr;
          size_t idx = (size_t)row * N + col;
          epi_store(EPI, outp, idx, epi_apply(EPI, acc[am][ni][rr], col, idx, bias, resid));
        }
  }
}

// ============ pipelined persistent 8-phase 256x256 GEMM (mlp1) ============
template <int CMH, int CS, int CB, int RBUF, int RMH, int RKH, int RB, int VM, int NORD,
          typename STF>
__device__ __forceinline__ void gphQ(const char* aB0, const char* bB0,
                                     s16x8 (&af2)[2][4], s16x8 (&bk2)[2][4],
                                     f32x4 (&acc)[8][4], STF&& stage) {
  stage();
  if (VM == 10) asm volatile("s_waitcnt vmcnt(10)");
  if (VM == 4) asm volatile("s_waitcnt vmcnt(4)");
  if (VM == 0) asm volatile("s_waitcnt vmcnt(0)");
  __builtin_amdgcn_s_barrier();
  if (!NORD) {
    const char* aP = aB0 + RBUF * 32768 + RKH * 16384 + RMH * 4096;
#pragma unroll
    for (int mi = 0; mi < 4; ++mi) af2[CS ^ 1][mi] = *(const s16x8*)(aP + mi * 1024);
    if (RMH == 0) {
      const char* bP = bB0 + RBUF * 32768 + RKH * 16384;
#pragma unroll
      for (int ni = 0; ni < 4; ++ni) bk2[RB][ni] = *(const s16x8*)(bP + ni * 1024);
    }
  }
  __builtin_amdgcn_s_setprio(1);
#pragma unroll
  for (int mi = 0; mi < 4; ++mi)
#pragma unroll
    for (int ni = 0; ni < 4; ++ni)
      acc[CMH * 4 + mi][ni] = __builtin_amdgcn_mfma_f32_16x16x32_bf16(
          af2[CS][mi], bk2[CB][ni], acc[CMH * 4 + mi][ni], 0, 0, 0);
  __builtin_amdgcn_s_setprio(0);
  __builtin_amdgcn_s_barrier();
}

template <int EPI, int TPB>
__device__ __forceinline__ void gemm256_body(
    const unsigned short* __restrict__ A, const unsigned short* __restrict__ Bt,
    void* __restrict__ outp, const float* __restrict__ bias,
    const void* __restrict__ resid, int M, int N, int K, int ntn) {
  __shared__ char ldsc[131072];  // 128 KiB
  int tid = threadIdx.x;
  int lane = tid & 63, w = tid >> 6;
  int wm = w >> 2, wn = w & 3;
  int fr = lane & 15, q = lane >> 4;

  int nwg = gridDim.x, orig = blockIdx.x;
  int qd = nwg >> 3, r8 = nwg & 7, xcd = orig & 7, loc = orig >> 3;
  int bid = (xcd < r8 ? xcd * (qd + 1) : r8 * (qd + 1) + (xcd - r8) * qd) + loc;

  int rdoff = (q * 16) ^ (((fr >> 1) & 3) << 4);
  const char* aB0 = ldsc + (wm * 128 + fr) * 64 + rdoff;
  const char* bB0 = ldsc + 65536 + (wn * 64 + fr) * 64 + rdoff;

  int srow = tid >> 2;
  int seoff = (((tid & 3) ^ ((srow >> 1) & 3))) << 3;
  size_t rstep = (size_t)K * 256;
  int NT = K / 64;

#pragma unroll 1
  for (int tl = 0; tl < TPB; ++tl) {
    int tile = bid * TPB + tl;
    int m0 = (tile / ntn) * 256, n0 = (tile % ntn) * 256;

    const char* Ab = (const char*)A + ((size_t)(m0 + srow) * K + seoff) * 2;
    const char* Bb = (const char*)Bt + ((size_t)(n0 + srow) * K + seoff) * 2;

    auto stg = [&](int mat, int kh, int buf, int t) {
      const char* gp = (mat ? Bb : Ab) + t * 128 + kh * 64;
      unsigned short* lp =
          (unsigned short*)(ldsc + mat * 65536 + buf * 32768 + kh * 16384 + w * 1024);
      gload16((const unsigned short*)gp, lp);
      gload16((const unsigned short*)(gp + rstep), (unsigned short*)((char*)lp + 8192));
    };
    auto nop = [&] {};

    f32x4 acc[8][4] = {};
    s16x8 af2[2][4], bk2[2][4];

    stg(1, 0, 0, 0);
    stg(0, 0, 0, 0);
    stg(1, 1, 0, 0);
    stg(0, 1, 0, 0);
    stg(1, 0, 1, 1);
    stg(0, 0, 1, 1);
    stg(1, 1, 1, 1);
    asm volatile("s_waitcnt vmcnt(6)");
    __builtin_amdgcn_s_barrier();
    {
#pragma unroll
      for (int mi = 0; mi < 4; ++mi) af2[0][mi] = *(const s16x8*)(aB0 + mi * 1024);
#pragma unroll
      for (int ni = 0; ni < 4; ++ni) bk2[0][ni] = *(const s16x8*)(bB0 + ni * 1024);
    }

    for (int t = 0; t + 3 < NT; t += 2) {
      gphQ<0, 0, 0, 0, 1, 0, 0, -1, 0>(aB0, bB0, af2, bk2, acc,
          [&] { stg(0, 1, 1, t + 1); });
      gphQ<1, 1, 0, 0, 0, 1, 1, 10, 0>(aB0, bB0, af2, bk2, acc,
          [&] { stg(1, 0, 0, t + 2); });
      gphQ<0, 0, 1, 0, 1, 1, 0, -1, 0>(aB0, bB0, af2, bk2, acc,
          [&] { stg(0, 0, 0, t + 2); });
      gphQ<1, 1, 1, 1, 0, 0, 0, 10, 0>(aB0, bB0, af2, bk2, acc,
          [&] { stg(1, 1, 0, t + 2); });
      gphQ<0, 0, 0, 1, 1, 0, 0, -1, 0>(aB0, bB0, af2, bk2, acc,
          [&] { stg(0, 1, 0, t + 2); });
      gphQ<1, 1, 0, 1, 0, 1, 1, 10, 0>(aB0, bB0, af2, bk2, acc,
          [&] { stg(1, 0, 1, t + 3); });
      gphQ<0, 0, 1, 1, 1, 1, 0, -1, 0>(aB0, bB0, af2, bk2, acc,
          [&] { stg(0, 0, 1, t + 3); });
      gphQ<1, 1, 1, 0, 0, 0, 0, 10, 0>(aB0, bB0, af2, bk2, acc,
          [&] { stg(1, 1, 1, t + 3); });
    }
    gphQ<0, 0, 0, 0, 1, 0, 0, -1, 0>(aB0, bB0, af2, bk2, acc,
        [&] { stg(0, 1, 1, NT - 1); });
    gphQ<1, 1, 0, 0, 0, 1, 1, -1, 0>(aB0, bB0, af2, bk2, acc, nop);
    gphQ<0, 0, 1, 0, 1, 1, 0, -1, 0>(aB0, bB0, af2, bk2, acc, nop);
    gphQ<1, 1, 1, 1, 0, 0, 0, 4, 0>(aB0, bB0, af2, bk2, acc, nop);
    gphQ<0, 0, 0, 1, 1, 0, 0, -1, 0>(aB0, bB0, af2, bk2, acc, nop);
    gphQ<1, 1, 0, 1, 0, 1, 1, 0, 0>(aB0, bB0, af2, bk2, acc, nop);
    gphQ<0, 0, 1, 1, 1, 1, 0, -1, 0>(aB0, bB0, af2, bk2, acc, nop);
    gphQ<1, 1, 1, 0, 0, 0, 0, -1, 1>(aB0, bB0, af2, bk2, acc, nop);

#pragma unroll
    for (int am = 0; am < 8; ++am)
#pragma unroll
      for (int ni = 0; ni < 4; ++ni)
#pragma unroll
        for (int rr = 0; rr < 4; ++rr) {
          int row = m0 + wm * 128 + am * 16 + q * 4 + rr;
          int col = n0 + wn * 64 + ni * 16 + fr;
          size_t idx = (size_t)row * N + col;
          epi_store(EPI, outp, idx, epi_apply(EPI, acc[am][ni][rr], col, idx, bias, resid));
        }
  }
}

// named wrappers for rocprof attribution
__global__ __launch_bounds__(512, 2) void gemm_qkv(const unsigned short* A,
                                                   const unsigned short* Bt, void* o,
                                                   const float* b, const void* r, int M,
                                                   int N, int K, int ntn) {
  gemm192_body<0, 3>(A, Bt, o, b, r, M, N, K, ntn);
}
__global__ __launch_bounds__(512, 2) void gemm_mlp1(const unsigned short* A,
                                                    const unsigned short* Bt, void* o,
                                                    const float* b, const void* r, int M,
                                                    int N, int K, int ntn) {
  gemm256_body<2, 3>(A, Bt, o, b, r, M, N, K, ntn);
}
__global__ __launch_bounds__(512, 2) void gemm_proj(const unsigned short* A,
                                                    const unsigned short* Bt, void* o,
                                                    const float* b, const void* r, int M,
                                                    int N, int K, int ntn) {
  gemm192_body<3, 1>(A, Bt, o, b, r, M, N, K, ntn);
}
__global__ __launch_bounds__(512, 2) void gemm_mlp2(const unsigned short* A,
                                                    const unsigned short* Bt, void* o,
                                                    const float* b, const void* r, int M,
                                                    int N, int K, int ntn) {
  gemm192_body<4, 1>(A, Bt, o, b, r, M, N, K, ntn);
}

// ---------------- MFMA attention: one wave per (batch, head) ----------------
__global__ __launch_bounds__(256) void attn_mfma_kernel(const unsigned short* __restrict__ qkv,
                                                        const float* __restrict__ scale,
                                                        unsigned short* __restrict__ ao) {
  __shared__ unsigned short Vt[4][64][40];
  __shared__ unsigned short Pl[4][32][32];
  int wid = threadIdx.x >> 6, lane = threadIdx.x & 63;
  int pair = blockIdx.x * 4 + wid;
  int b = pair / HEADS, h = pair % HEADS;
  const unsigned short* base = qkv + (size_t)b * NTOK * QKVN + h * DHEAD;
  const unsigned short* Qp = base;
  const unsigned short* Kp = base + 768;
  const unsigned short* Vp = base + 1536;

  int c = lane & 15, q = lane >> 4;
  int oct = q * 8;

  unsigned short vcol[NTOK];
#pragma unroll
  for (int j = 0; j < NTOK; ++j) vcol[j] = Vp[(size_t)j * QKVN + lane];
#pragma unroll
  for (int j = 0; j < NTOK; ++j) Vt[wid][lane][j] = vcol[j];
  Vt[wid][lane][31] = 0;

  s16x8 kf[2][2] = {{{0}}}, qf[2][2] = {{{0}}};
#pragma unroll
  for (int t = 0; t < 2; ++t) {
    int row = t * 16 + c;
    if (row < NTOK) {
#pragma unroll
      for (int s = 0; s < 2; ++s) {
        kf[t][s] = *(const s16x8*)(Kp + (size_t)row * QKVN + s * 32 + oct);
        qf[t][s] = *(const s16x8*)(Qp + (size_t)row * QKVN + s * 32 + oct);
      }
    }
  }

  f32x4 st[2][2] = {};
#pragma unroll
  for (int jt = 0; jt < 2; ++jt)
#pragma unroll
    for (int it = 0; it < 2; ++it)
#pragma unroll
      for (int s = 0; s < 2; ++s)
        st[jt][it] =
            __builtin_amdgcn_mfma_f32_16x16x32_bf16(kf[jt][s], qf[it][s], st[jt][it], 0, 0, 0);

  float scl = scale[h];
  float p[2][2][4];
#pragma unroll
  for (int it = 0; it < 2; ++it)
#pragma unroll
    for (int jt = 0; jt < 2; ++jt)
#pragma unroll
      for (int r = 0; r < 4; ++r) {
        int j = jt * 16 + 4 * q + r;
        int i = it * 16 + c;
        float v = st[jt][it][r] * scl;
        if (j == 31 || j == i) v = MASK_VAL;
        p[it][jt][r] = v;
      }
#pragma unroll
  for (int it = 0; it < 2; ++it) {
    float m = p[it][0][0];
#pragma unroll
    for (int jt = 0; jt < 2; ++jt)
#pragma unroll
      for (int r = 0; r < 4; ++r) m = fmaxf(m, p[it][jt][r]);
    m = fmaxf(m, __shfl_xor(m, 16));
    m = fmaxf(m, __shfl_xor(m, 32));
    float s = 0.f;
#pragma unroll
    for (int jt = 0; jt < 2; ++jt)
#pragma unroll
      for (int r = 0; r < 4; ++r) {
        float e = __expf(p[it][jt][r] - m);
        p[it][jt][r] = e;
        s += e;
      }
    s += __shfl_xor(s, 16);
    s += __shfl_xor(s, 32);
    float inv = __builtin_amdgcn_rcpf(s);
#pragma unroll
    for (int jt = 0; jt < 2; ++jt)
#pragma unroll
      for (int r = 0; r < 4; ++r) p[it][jt][r] *= inv;
  }
#pragma unroll
  for (int it = 0; it < 2; ++it)
#pragma unroll
    for (int jt = 0; jt < 2; ++jt) {
      unsigned int w0 =
          (unsigned int)f2bs(p[it][jt][0]) | ((unsigned int)f2bs(p[it][jt][1]) << 16);
      unsigned int w1 =
          (unsigned int)f2bs(p[it][jt][2]) | ((unsigned int)f2bs(p[it][jt][3]) << 16);
      uint2 pk = {w0, w1};
      *(uint2*)&Pl[wid][it * 16 + c][jt * 16 + 4 * q] = pk;
    }

  s16x8 pa[2];
#pragma unroll
  for (int it = 0; it < 2; ++it) pa[it] = *(const s16x8*)&Pl[wid][it * 16 + c][oct];
  f32x4 o[2][4];
#pragma unroll
  for (int it = 0; it < 2; ++it)
#pragma unroll
    for (int dt = 0; dt < 4; ++dt) {
      s16x8 vb = *(const s16x8*)&Vt[wid][dt * 16 + c][oct];
      f32x4 z = {0.f, 0.f, 0.f, 0.f};
      o[it][dt] = __builtin_amdgcn_mfma_f32_16x16x32_bf16(pa[it], vb, z, 0, 0, 0);
    }
#pragma unroll
  for (int it = 0; it < 2; ++it)
#pragma unroll
    for (int r = 0; r < 4; ++r) {
      int i = it * 16 + 4 * q + r;
      if (i < NTOK) {
        size_t rowoff = ((size_t)b * NTOK + i) * DIM + h * DHEAD;
#pragma unroll
        for (int dt = 0; dt < 4; ++dt) ao[rowoff + dt * 16 + c] = f2bs(o[it][dt][r]);
      }
    }
}

// ---------------- launcher ----------------
extern "C" void kernel_launch(void* const* d_in, const int* in_sizes, int n_in,
                              void* d_out, int out_size, void* d_ws, size_t ws_size,
                              hipStream_t stream) {
  (void)in_sizes; (void)n_in; (void)out_size; (void)ws_size;
  const float* x = (const float*)d_in[0];
  const float* ln1_g = (const float*)d_in[1];
  const float* ln1_b = (const float*)d_in[2];
  const float* w_qkv = (const float*)d_in[3];
  const float* scale = (const float*)d_in[4];
  const float* w_o = (const float*)d_in[5];
  const float* b_o = (const float*)d_in[6];
  const float* ln2_g = (const float*)d_in[7];
  const float* ln2_b = (const float*)d_in[8];
  const float* w1 = (const float*)d_in[9];
  const float* b1 = (const float*)d_in[10];
  const float* w2 = (const float*)d_in[11];
  const float* b2 = (const float*)d_in[12];

  char* ws = (char*)d_ws;
  unsigned short* buf1 = (unsigned short*)(ws + 0);
  unsigned short* qkv_bf = (unsigned short*)(ws + 24379392);
  unsigned short* x2 = (unsigned short*)(ws + 24379392);  // aliases qkv (qkv dead)
  unsigned short* g_bf = (unsigned short*)(ws + 97517568);
  unsigned short* wqkvT = (unsigned short*)(ws + 195035136);  // flat [2304][768]
  unsigned short* woT = (unsigned short*)(ws + 198574080);    // flat [768][768]
  unsigned short* w1T = (unsigned short*)(ws + 199753728);    // flat [3072][768]
  unsigned short* w2T = (unsigned short*)(ws + 204472320);    // flat [768][3072]

  transpose_all_kernel<<<1728, 256, 0, stream>>>(w_qkv, w_o, w1, w2, wqkvT, woT, w1T, w2T);

  ln_kernel<<<MTOK / 4, 256, 0, stream>>>(x, ln1_g, ln1_b, buf1);
  // qkv GEMM   [256x192, 744 tiles, TPB=3 -> grid 248]
  gemm_qkv<<<248, 512, 0, stream>>>(
      buf1, wqkvT, qkv_bf, nullptr, nullptr, MTOK, QKVN, DIM, QKVN / 192);
  attn_mfma_kernel<<<(BATCH * HEADS) / 4, 256, 0, stream>>>(qkv_bf, scale, buf1);
  // proj + residual(x, f32) -> x2 (bf16)   [248 tiles, TPB=1]
  gemm_proj<<<248, 512, 0, stream>>>(
      buf1, woT, x2, b_o, x, MTOK, DIM, DIM, DIM / 192);
  ln_bf16_kernel<<<MTOK / 4, 256, 0, stream>>>(x2, ln2_g, ln2_b, buf1);
  // mlp1 + tanh-GELU   [256x256, 744 tiles, TPB=3 -> grid 248]
  gemm_mlp1<<<248, 512, 0, stream>>>(
      buf1, w1T, g_bf, b1, nullptr, MTOK, HIDDEN, DIM, HIDDEN / 256);
  // mlp2 + residual(x2, bf16) -> out (f32)   [248 tiles, TPB=1]
  gemm_mlp2<<<248, 512, 0, stream>>>(
      g_bf, w2T, (float*)d_out, b2, x2, MTOK, DIM, HIDDEN, DIM / 192);
}